// Round 6
// baseline (149.046 us; speedup 1.0000x reference)
//
#include <hip/hip_runtime.h>
#include <hip/hip_bf16.h>

#define NN 64
#define CC 512
#define MM 1600
#define KK 64
#define EPSF 1e-12f
#define PP 4   // m-partitions (partial agg buffers)

typedef __attribute__((ext_vector_type(4))) float f32x4;
typedef __attribute__((ext_vector_type(8))) short bf16x8;

__device__ inline unsigned short f2bf(float f) {
    unsigned int u = __float_as_uint(f);
    unsigned int r = u + 0x7fffu + ((u >> 16) & 1u);   // RNE
    return (unsigned short)(r >> 16);
}

// ---------------------------------------------------------------------------
// w -> bf16
// ---------------------------------------------------------------------------
__global__ __launch_bounds__(256) void wconv_kernel(
    const float* __restrict__ w, unsigned short* __restrict__ wb)
{
    const int i = (blockIdx.x * 256 + threadIdx.x) * 8;
    float4 a = *(const float4*)(w + i);
    float4 b = *(const float4*)(w + i + 4);
    ushort4 u0, u1;
    u0.x = f2bf(a.x); u0.y = f2bf(a.y); u0.z = f2bf(a.z); u0.w = f2bf(a.w);
    u1.x = f2bf(b.x); u1.y = f2bf(b.y); u1.z = f2bf(b.z); u1.w = f2bf(b.w);
    *(ushort4*)(wb + i) = u0;
    *(ushort4*)(wb + i + 4) = u1;
}

// ---------------------------------------------------------------------------
// mega: per (m-part p, n): loop m-tiles of 128:
//   phase1: logits MFMA (x scalar-coalesced from HBM, f2bf in-reg) + rnorm
//   phase2: register softmax over K (shfl), a' -> LDS apl[64k][128m] bf16
//   phase3: agg MFMA D[k64][c64/wave] += a'(LDS) x x(global f32, L2/L3-hot)
// agg acc lives in VGPRs across tiles; partial agg + asum written at end.
// grid (PP, NN), 512 threads (8 waves). Tiles: p0:{0..3} p1:{4..6} p2:{7..9}
// p3:{10..12}; tile 12 is the 64-m tail (masked).
// ---------------------------------------------------------------------------
__global__ __launch_bounds__(512) void mega_kernel(
    const float* __restrict__ x, const unsigned short* __restrict__ wb,
    const float* __restrict__ bias,
    float* __restrict__ aggp, float* __restrict__ asum_part)
{
    __shared__ __attribute__((aligned(16))) unsigned short apl[64][136]; // pad->2-way
    __shared__ float asum_l[8][64];

    const int t    = threadIdx.x;
    const int p    = blockIdx.x;
    const int n    = blockIdx.y;
    const int wv   = t >> 6;
    const int lane = t & 63;
    const int g    = lane >> 4;
    const int lr   = lane & 15;
    const int c0   = wv * 64;

    const int t_beg = (p == 0) ? 0 : 1 + 3 * p;   // 0,4,7,10
    const int nt    = (p == 0) ? 4 : 3;

    f32x4 agg_acc[4][4];
    #pragma unroll
    for (int kt = 0; kt < 4; ++kt)
        #pragma unroll
        for (int ct = 0; ct < 4; ++ct) agg_acc[kt][ct] = (f32x4){0.f, 0.f, 0.f, 0.f};
    float asum_acc[16];
    #pragma unroll
    for (int i = 0; i < 16; ++i) asum_acc[i] = 0.f;

    for (int ti = 0; ti < nt; ++ti) {
        const int m0     = (t_beg + ti) * 128;
        const int m_lane = m0 + wv * 16 + lr;
        const bool mok   = m_lane < MM;           // wave-uniform

        // ---- phase 1: logits D[k64][m16 per wave] over C=512 ----
        f32x4 lacc[4];
        #pragma unroll
        for (int kt = 0; kt < 4; ++kt) lacc[kt] = (f32x4){0.f, 0.f, 0.f, 0.f};
        float ss = 0.f;
        const float* xcol = x + (size_t)n * CC * MM + m_lane;
        const unsigned short* wrow = wb + g * 8;

        #pragma unroll 2
        for (int cs = 0; cs < 16; ++cs) {
            const int cbase = cs * 32 + g * 8;
            float xv[8];
            #pragma unroll
            for (int j = 0; j < 8; ++j)
                xv[j] = mok ? xcol[(size_t)(cbase + j) * MM] : 0.f;
            bf16x8 bfrag;
            #pragma unroll
            for (int j = 0; j < 8; ++j) {
                ss += xv[j] * xv[j];
                bfrag[j] = (short)f2bf(xv[j]);
            }
            #pragma unroll
            for (int kt = 0; kt < 4; ++kt) {
                bf16x8 afrag = *(const bf16x8*)(wrow + (kt * 16 + lr) * CC + cs * 32);
                lacc[kt] = __builtin_amdgcn_mfma_f32_16x16x32_bf16(afrag, bfrag, lacc[kt], 0, 0, 0);
            }
        }

        ss += __shfl_xor(ss, 16);
        ss += __shfl_xor(ss, 32);
        const float rnm = 1.0f / fmaxf(sqrtf(ss), EPSF);

        // ---- phase 2: softmax over k (register + shfl) ----
        float l[16];
        #pragma unroll
        for (int kt = 0; kt < 4; ++kt) {
            float4 bb = *(const float4*)(bias + kt * 16 + g * 4);
            l[kt * 4 + 0] = lacc[kt][0] * rnm + bb.x;
            l[kt * 4 + 1] = lacc[kt][1] * rnm + bb.y;
            l[kt * 4 + 2] = lacc[kt][2] * rnm + bb.z;
            l[kt * 4 + 3] = lacc[kt][3] * rnm + bb.w;
        }
        float mx = l[0];
        #pragma unroll
        for (int i = 1; i < 16; ++i) mx = fmaxf(mx, l[i]);
        mx = fmaxf(mx, __shfl_xor(mx, 16));
        mx = fmaxf(mx, __shfl_xor(mx, 32));
        float s = 0.f;
        #pragma unroll
        for (int i = 0; i < 16; ++i) { l[i] = __expf(l[i] - mx); s += l[i]; }
        s += __shfl_xor(s, 16);
        s += __shfl_xor(s, 32);
        const float inv = 1.0f / s;

        __syncthreads();   // S1: previous tile's phase-3 apl readers done
        #pragma unroll
        for (int kt = 0; kt < 4; ++kt)
            #pragma unroll
            for (int r = 0; r < 4; ++r) {
                const float av = l[kt * 4 + r] * inv;    // normalized a
                unsigned short ub = 0;
                if (mok) {
                    asum_acc[kt * 4 + r] += av;
                    ub = f2bf(av * rnm);                 // a' = a*rnorm
                }
                apl[kt * 16 + g * 4 + r][wv * 16 + lr] = ub;
            }
        __syncthreads();   // S2: apl visible

        // ---- phase 3: agg D[k64][c64 per wave] += a'[k][m] * x[c][m] ----
        const int smax = (MM - m0 >= 128) ? 4 : (MM - m0) / 32;
        for (int ms = 0; ms < smax; ++ms) {
            bf16x8 af[4];
            #pragma unroll
            for (int kt = 0; kt < 4; ++kt)
                af[kt] = *(const bf16x8*)&apl[kt * 16 + lr][ms * 32 + g * 8];
            #pragma unroll
            for (int ct = 0; ct < 4; ++ct) {
                const float* xr = x + ((size_t)(n * CC + c0 + ct * 16 + lr)) * MM
                                    + m0 + ms * 32 + g * 8;
                float4 v0 = *(const float4*)xr;
                float4 v1 = *(const float4*)(xr + 4);
                bf16x8 bf;
                bf[0] = (short)f2bf(v0.x); bf[1] = (short)f2bf(v0.y);
                bf[2] = (short)f2bf(v0.z); bf[3] = (short)f2bf(v0.w);
                bf[4] = (short)f2bf(v1.x); bf[5] = (short)f2bf(v1.y);
                bf[6] = (short)f2bf(v1.z); bf[7] = (short)f2bf(v1.w);
                #pragma unroll
                for (int kt = 0; kt < 4; ++kt)
                    agg_acc[kt][ct] = __builtin_amdgcn_mfma_f32_16x16x32_bf16(af[kt], bf, agg_acc[kt][ct], 0, 0, 0);
            }
        }
    }

    // ---- epilogue: partial agg store (plain, coalesced over lr) ----
    #pragma unroll
    for (int kt = 0; kt < 4; ++kt)
        #pragma unroll
        for (int ct = 0; ct < 4; ++ct)
            #pragma unroll
            for (int r = 0; r < 4; ++r) {
                const int k = kt * 16 + g * 4 + r;
                aggp[((size_t)((p * NN + n) * KK + k)) * CC + c0 + ct * 16 + lr]
                    = agg_acc[kt][ct][r];
            }

    // ---- asum: reduce over lr lanes, then over 8 waves via LDS ----
    #pragma unroll
    for (int i = 0; i < 16; ++i) {
        asum_acc[i] += __shfl_xor(asum_acc[i], 1);
        asum_acc[i] += __shfl_xor(asum_acc[i], 2);
        asum_acc[i] += __shfl_xor(asum_acc[i], 4);
        asum_acc[i] += __shfl_xor(asum_acc[i], 8);
    }
    if (lr == 0) {
        #pragma unroll
        for (int kt = 0; kt < 4; ++kt)
            #pragma unroll
            for (int r = 0; r < 4; ++r)
                asum_l[wv][kt * 16 + g * 4 + r] = asum_acc[kt * 4 + r];
    }
    __syncthreads();
    if (t < 64) {
        float sa = 0.f;
        #pragma unroll
        for (int w8 = 0; w8 < 8; ++w8) sa += asum_l[w8][t];
        asum_part[((size_t)(p * NN + n)) * KK + t] = sa;
    }
}

// ---------------------------------------------------------------------------
// vlad = (sum of 4 agg partials) - asum*cent, intra-normalize over C
// ---------------------------------------------------------------------------
__global__ __launch_bounds__(256) void vlad_kernel(
    const float* __restrict__ aggp, const float* __restrict__ asum_part,
    const float* __restrict__ cent, float* __restrict__ out,
    float* __restrict__ gns_part)
{
    __shared__ float wsum[4];
    __shared__ float sinv;
    const int nk = blockIdx.x;          // n*64 + k
    const int n = nk >> 6, k = nk & 63;
    const int t = threadIdx.x;
    const int u = t & 63;
    const size_t part = (size_t)NN * KK * CC;

    // reduce asum over PP part partials (each wave redundantly)
    float pa = (u < PP) ? asum_part[((size_t)(u * NN + n)) * KK + k] : 0.f;
    #pragma unroll
    for (int o = 32; o > 0; o >>= 1) pa += __shfl_xor(pa, o);
    const float s = pa;

    float2 a0 = *(const float2*)(aggp + 0 * part + (size_t)nk * CC + 2 * t);
    float2 a1 = *(const float2*)(aggp + 1 * part + (size_t)nk * CC + 2 * t);
    float2 a2 = *(const float2*)(aggp + 2 * part + (size_t)nk * CC + 2 * t);
    float2 a3 = *(const float2*)(aggp + 3 * part + (size_t)nk * CC + 2 * t);
    float2 cv = *(const float2*)(cent + (size_t)k * CC + 2 * t);
    float v0 = (a0.x + a1.x) + (a2.x + a3.x) - s * cv.x;
    float v1 = (a0.y + a1.y) + (a2.y + a3.y) - s * cv.y;
    float ss = v0 * v0 + v1 * v1;
    #pragma unroll
    for (int o = 32; o > 0; o >>= 1) ss += __shfl_down(ss, o);
    int wid = t >> 6;
    if (u == 0) wsum[wid] = ss;
    __syncthreads();
    if (t == 0) {
        float tot = wsum[0] + wsum[1] + wsum[2] + wsum[3];
        float inv = 1.0f / fmaxf(sqrtf(tot), EPSF);
        sinv = inv;
        gns_part[nk] = tot * inv * inv;
    }
    __syncthreads();
    float inv = sinv;
    float2 o2; o2.x = v0 * inv; o2.y = v1 * inv;
    *(float2*)(out + (size_t)nk * CC + 2 * t) = o2;
}

// ---------------------------------------------------------------------------
// global L2 scale per n (reduce 64 gns partials per wave, redundantly)
// ---------------------------------------------------------------------------
__global__ __launch_bounds__(256) void gscale_kernel(
    float* __restrict__ out, const float* __restrict__ gns_part)
{
    const int idx = blockIdx.x * 256 + threadIdx.x;   // float4 index
    const int n = blockIdx.x >> 5;                    // 32 blocks per n
    const int u = threadIdx.x & 63;
    float g = gns_part[n * 64 + u];
    #pragma unroll
    for (int o = 32; o > 0; o >>= 1) g += __shfl_xor(g, o);
    float inv = 1.0f / fmaxf(sqrtf(g), EPSF);
    float4 v = *(float4*)(out + (size_t)idx * 4);
    v.x *= inv; v.y *= inv; v.z *= inv; v.w *= inv;
    *(float4*)(out + (size_t)idx * 4) = v;
}

extern "C" void kernel_launch(void* const* d_in, const int* in_sizes, int n_in,
                              void* d_out, int out_size, void* d_ws, size_t ws_size,
                              hipStream_t stream)
{
    const float* x    = (const float*)d_in[0];
    const float* w    = (const float*)d_in[1];
    const float* bias = (const float*)d_in[2];
    const float* cent = (const float*)d_in[3];
    float* out = (float*)d_out;

    char* ws = (char*)d_ws;
    size_t off = 0;
    unsigned short* wb = (unsigned short*)(ws + off); off += (size_t)KK * CC * 2;
    float* aggp      = (float*)(ws + off); off += (size_t)PP * NN * KK * CC * 4;
    float* asum_part = (float*)(ws + off); off += (size_t)PP * NN * KK * 4;
    float* gns_part  = (float*)(ws + off); off += (size_t)NN * KK * 4;

    wconv_kernel <<<16, 256, 0, stream>>>(w, wb);
    mega_kernel  <<<dim3(PP, NN), 512, 0, stream>>>(x, wb, bias, aggp, asum_part);
    vlad_kernel  <<<NN * KK, 256, 0, stream>>>(aggp, asum_part, cent, out, gns_part);
    gscale_kernel<<<(out_size / 4 + 255) / 256, 256, 0, stream>>>(out, gns_part);
}

// Round 7
// 148.819 us; speedup vs baseline: 1.0015x; 1.0015x over previous
//
#include <hip/hip_runtime.h>
#include <hip/hip_bf16.h>

#define NN 64
#define CC 512
#define MM 1600
#define KK 64
#define EPSF 1e-12f
#define PP 8   // m-partitions (partial agg buffers)

typedef __attribute__((ext_vector_type(4))) float f32x4;
typedef __attribute__((ext_vector_type(8))) short bf16x8;

__device__ inline unsigned short f2bf(float f) {
    unsigned int u = __float_as_uint(f);
    unsigned int r = u + 0x7fffu + ((u >> 16) & 1u);   // RNE
    return (unsigned short)(r >> 16);
}

// ---------------------------------------------------------------------------
// w -> bf16
// ---------------------------------------------------------------------------
__global__ __launch_bounds__(256) void wconv_kernel(
    const float* __restrict__ w, unsigned short* __restrict__ wb)
{
    const int i = (blockIdx.x * 256 + threadIdx.x) * 8;
    float4 a = *(const float4*)(w + i);
    float4 b = *(const float4*)(w + i + 4);
    ushort4 u0, u1;
    u0.x = f2bf(a.x); u0.y = f2bf(a.y); u0.z = f2bf(a.z); u0.w = f2bf(a.w);
    u1.x = f2bf(b.x); u1.y = f2bf(b.y); u1.z = f2bf(b.z); u1.w = f2bf(b.w);
    *(ushort4*)(wb + i) = u0;
    *(ushort4*)(wb + i + 4) = u1;
}

// ---------------------------------------------------------------------------
// mega-v2: per (p, n), loop over this partition's 64-m tiles:
//   stage:  x f32 global (coalesced float4) -> bf16 -> swizzled LDS [512c][64m]
//   phase1: logits MFMA from LDS (c-run u16 reads) + sumsq(bf16) -> rnorm
//           -> register softmax over K -> apl bf16 [64k][64m] in LDS
//   phase3: agg MFMA D[64k][128c per wave] += apl x xl (both LDS, b128 reads)
// agg acc in VGPRs across tiles; partial agg + asum stored at end.
// grid (PP, NN), 256 threads (4 waves). Tiles: p0:{0..3}, p>=1:{4+3(p-1)..+3}.
// LDS: xl 64KB + apl 9.2KB + asum 1KB = 74.5KB -> 2 blocks/CU.
// ---------------------------------------------------------------------------
__global__ __launch_bounds__(256, 2) void mega_kernel(
    const float* __restrict__ x, const unsigned short* __restrict__ wb,
    const float* __restrict__ bias,
    float* __restrict__ aggp, float* __restrict__ asum_part)
{
    __shared__ __attribute__((aligned(16))) unsigned char xl[65536];    // swizzled
    __shared__ __attribute__((aligned(16))) unsigned short apl[64][72]; // pad: 2-way
    __shared__ float asum_l[4][64];

    const int t    = threadIdx.x;
    const int p    = blockIdx.x;
    const int n    = blockIdx.y;
    const int wv   = t >> 6;
    const int lane = t & 63;
    const int g    = lane >> 4;
    const int lr   = lane & 15;

    const int t_beg = (p == 0) ? 0 : 4 + 3 * (p - 1);
    const int nt    = (p == 0) ? 4 : 3;

    f32x4 acc[4][8];   // [kt][ct]: k = kt*16+g*4+r, c = wv*128+ct*16+lr
    #pragma unroll
    for (int kt = 0; kt < 4; ++kt)
        #pragma unroll
        for (int ct = 0; ct < 8; ++ct) acc[kt][ct] = (f32x4){0.f, 0.f, 0.f, 0.f};
    float asum_acc[16];
    #pragma unroll
    for (int i = 0; i < 16; ++i) asum_acc[i] = 0.f;

    const int sc  = t >> 4;    // staging row-within-group
    const int sm  = t & 15;    // staging m-quad
    const unsigned int skey = ((unsigned)(sc & 7)) << 4;

    for (int ti = 0; ti < nt; ++ti) {
        const int m0 = (t_beg + ti) * 64;

        __syncthreads();   // prev tile's phase-3 done reading xl
        // ---- stage: x[512c][64m] f32 -> bf16 swizzled LDS ----
        {
            const float* xb = x + (size_t)n * CC * MM + m0 + sm * 4;
            #pragma unroll 8
            for (int i = 0; i < 32; ++i) {
                const int c = i * 16 + sc;
                float4 v = *(const float4*)(xb + (size_t)c * MM);
                ushort4 b;
                b.x = f2bf(v.x); b.y = f2bf(v.y); b.z = f2bf(v.z); b.w = f2bf(v.w);
                *(ushort4*)(xl + (unsigned)(c * 128) + (((unsigned)(sm * 8)) ^ skey)) = b;
            }
        }
        __syncthreads();   // xl ready

        // ---- phase 1: logits D[64k][16m per wave] over C=512 ----
        f32x4 lacc[4];
        #pragma unroll
        for (int kt = 0; kt < 4; ++kt) lacc[kt] = (f32x4){0.f, 0.f, 0.f, 0.f};
        float ss = 0.f;
        const int mloc2 = (wv * 16 + lr) * 2;
        const unsigned short* wrow = wb + g * 8;

        #pragma unroll 2
        for (int cs = 0; cs < 16; ++cs) {
            const int cb = cs * 32 + g * 8;
            bf16x8 bfrag;
            #pragma unroll
            for (int j = 0; j < 8; ++j) {
                unsigned short u = *(const unsigned short*)(
                    xl + (unsigned)((cb + j) * 128) + (((unsigned)mloc2) ^ ((unsigned)j << 4)));
                bfrag[j] = (short)u;
                float f = __uint_as_float(((unsigned int)u) << 16);
                ss += f * f;
            }
            #pragma unroll
            for (int kt = 0; kt < 4; ++kt) {
                bf16x8 afrag = *(const bf16x8*)(wrow + (kt * 16 + lr) * CC + cs * 32);
                lacc[kt] = __builtin_amdgcn_mfma_f32_16x16x32_bf16(afrag, bfrag, lacc[kt], 0, 0, 0);
            }
        }

        ss += __shfl_xor(ss, 16);
        ss += __shfl_xor(ss, 32);
        const float rnm = 1.0f / fmaxf(sqrtf(ss), EPSF);

        // ---- phase 2: softmax over k (registers + shfl) ----
        float l[16];
        #pragma unroll
        for (int kt = 0; kt < 4; ++kt) {
            float4 bb = *(const float4*)(bias + kt * 16 + g * 4);
            l[kt * 4 + 0] = lacc[kt][0] * rnm + bb.x;
            l[kt * 4 + 1] = lacc[kt][1] * rnm + bb.y;
            l[kt * 4 + 2] = lacc[kt][2] * rnm + bb.z;
            l[kt * 4 + 3] = lacc[kt][3] * rnm + bb.w;
        }
        float mx = l[0];
        #pragma unroll
        for (int i = 1; i < 16; ++i) mx = fmaxf(mx, l[i]);
        mx = fmaxf(mx, __shfl_xor(mx, 16));
        mx = fmaxf(mx, __shfl_xor(mx, 32));
        float s = 0.f;
        #pragma unroll
        for (int i = 0; i < 16; ++i) { l[i] = __expf(l[i] - mx); s += l[i]; }
        s += __shfl_xor(s, 16);
        s += __shfl_xor(s, 32);
        const float inv = 1.0f / s;

        #pragma unroll
        for (int kt = 0; kt < 4; ++kt)
            #pragma unroll
            for (int r = 0; r < 4; ++r) {
                const float av = l[kt * 4 + r] * inv;
                asum_acc[kt * 4 + r] += av;
                apl[kt * 16 + g * 4 + r][wv * 16 + lr] = f2bf(av * rnm);
            }
        __syncthreads();   // apl ready (xl still valid)

        // ---- phase 3: agg D[64k][128c per wave] += apl[k][m] * xl[c][m] ----
        #pragma unroll
        for (int ms = 0; ms < 2; ++ms) {
            bf16x8 af[4];
            #pragma unroll
            for (int kt = 0; kt < 4; ++kt)
                af[kt] = *(const bf16x8*)&apl[kt * 16 + lr][ms * 32 + g * 8];
            const unsigned moff = (unsigned)((ms * 32 + g * 8) * 2) ^ (((unsigned)(lr & 7)) << 4);
            #pragma unroll
            for (int ct = 0; ct < 8; ++ct) {
                const int c = wv * 128 + ct * 16 + lr;
                bf16x8 bf = *(const bf16x8*)(xl + (unsigned)(c * 128) + moff);
                #pragma unroll
                for (int kt = 0; kt < 4; ++kt)
                    acc[kt][ct] = __builtin_amdgcn_mfma_f32_16x16x32_bf16(af[kt], bf, acc[kt][ct], 0, 0, 0);
            }
        }
    }

    // ---- epilogue: partial agg store (coalesced over lr) ----
    #pragma unroll
    for (int kt = 0; kt < 4; ++kt)
        #pragma unroll
        for (int ct = 0; ct < 8; ++ct)
            #pragma unroll
            for (int r = 0; r < 4; ++r) {
                const int k = kt * 16 + g * 4 + r;
                const int c = wv * 128 + ct * 16 + lr;
                aggp[((size_t)((p * NN + n) * KK + k)) * CC + c] = acc[kt][ct][r];
            }

    // ---- asum: reduce over lr, then over 4 waves via LDS ----
    #pragma unroll
    for (int i = 0; i < 16; ++i) {
        asum_acc[i] += __shfl_xor(asum_acc[i], 1);
        asum_acc[i] += __shfl_xor(asum_acc[i], 2);
        asum_acc[i] += __shfl_xor(asum_acc[i], 4);
        asum_acc[i] += __shfl_xor(asum_acc[i], 8);
    }
    if (lr == 0) {
        #pragma unroll
        for (int kt = 0; kt < 4; ++kt)
            #pragma unroll
            for (int r = 0; r < 4; ++r)
                asum_l[wv][kt * 16 + g * 4 + r] = asum_acc[kt * 4 + r];
    }
    __syncthreads();
    if (t < 64) {
        float sa = asum_l[0][t] + asum_l[1][t] + asum_l[2][t] + asum_l[3][t];
        asum_part[((size_t)(p * NN + n)) * KK + t] = sa;
    }
}

// ---------------------------------------------------------------------------
// vlad = (sum of PP agg partials) - asum*cent, intra-normalize over C
// ---------------------------------------------------------------------------
__global__ __launch_bounds__(256) void vlad_kernel(
    const float* __restrict__ aggp, const float* __restrict__ asum_part,
    const float* __restrict__ cent, float* __restrict__ out,
    float* __restrict__ gns_part)
{
    __shared__ float wsum[4];
    __shared__ float sinv;
    const int nk = blockIdx.x;          // n*64 + k
    const int n = nk >> 6, k = nk & 63;
    const int t = threadIdx.x;
    const int u = t & 63;
    const size_t part = (size_t)NN * KK * CC;

    float pa = (u < PP) ? asum_part[((size_t)(u * NN + n)) * KK + k] : 0.f;
    #pragma unroll
    for (int o = 32; o > 0; o >>= 1) pa += __shfl_xor(pa, o);
    const float s = pa;

    float v0 = 0.f, v1 = 0.f;
    #pragma unroll
    for (int q = 0; q < PP; ++q) {
        float2 a = *(const float2*)(aggp + (size_t)q * part + (size_t)nk * CC + 2 * t);
        v0 += a.x; v1 += a.y;
    }
    float2 cv = *(const float2*)(cent + (size_t)k * CC + 2 * t);
    v0 -= s * cv.x;
    v1 -= s * cv.y;
    float ss = v0 * v0 + v1 * v1;
    #pragma unroll
    for (int o = 32; o > 0; o >>= 1) ss += __shfl_down(ss, o);
    int wid = t >> 6;
    if (u == 0) wsum[wid] = ss;
    __syncthreads();
    if (t == 0) {
        float tot = wsum[0] + wsum[1] + wsum[2] + wsum[3];
        float inv = 1.0f / fmaxf(sqrtf(tot), EPSF);
        sinv = inv;
        gns_part[nk] = tot * inv * inv;
    }
    __syncthreads();
    float inv = sinv;
    float2 o2; o2.x = v0 * inv; o2.y = v1 * inv;
    *(float2*)(out + (size_t)nk * CC + 2 * t) = o2;
}

// ---------------------------------------------------------------------------
// global L2 scale per n (reduce 64 gns partials per wave, redundantly)
// ---------------------------------------------------------------------------
__global__ __launch_bounds__(256) void gscale_kernel(
    float* __restrict__ out, const float* __restrict__ gns_part)
{
    const int idx = blockIdx.x * 256 + threadIdx.x;   // float4 index
    const int n = blockIdx.x >> 5;                    // 32 blocks per n
    const int u = threadIdx.x & 63;
    float g = gns_part[n * 64 + u];
    #pragma unroll
    for (int o = 32; o > 0; o >>= 1) g += __shfl_xor(g, o);
    float inv = 1.0f / fmaxf(sqrtf(g), EPSF);
    float4 v = *(float4*)(out + (size_t)idx * 4);
    v.x *= inv; v.y *= inv; v.z *= inv; v.w *= inv;
    *(float4*)(out + (size_t)idx * 4) = v;
}

extern "C" void kernel_launch(void* const* d_in, const int* in_sizes, int n_in,
                              void* d_out, int out_size, void* d_ws, size_t ws_size,
                              hipStream_t stream)
{
    const float* x    = (const float*)d_in[0];
    const float* w    = (const float*)d_in[1];
    const float* bias = (const float*)d_in[2];
    const float* cent = (const float*)d_in[3];
    float* out = (float*)d_out;

    char* ws = (char*)d_ws;
    size_t off = 0;
    unsigned short* wb = (unsigned short*)(ws + off); off += (size_t)KK * CC * 2;
    float* aggp      = (float*)(ws + off); off += (size_t)PP * NN * KK * CC * 4;
    float* asum_part = (float*)(ws + off); off += (size_t)PP * NN * KK * 4;
    float* gns_part  = (float*)(ws + off); off += (size_t)NN * KK * 4;

    wconv_kernel <<<16, 256, 0, stream>>>(w, wb);
    mega_kernel  <<<dim3(PP, NN), 256, 0, stream>>>(x, wb, bias, aggp, asum_part);
    vlad_kernel  <<<NN * KK, 256, 0, stream>>>(aggp, asum_part, cent, out, gns_part);
    gscale_kernel<<<(out_size / 4 + 255) / 256, 256, 0, stream>>>(out, gns_part);
}

// Round 8
// 124.599 us; speedup vs baseline: 1.1962x; 1.1944x over previous
//
#include <hip/hip_runtime.h>
#include <hip/hip_bf16.h>

#define NN 64
#define CC 512
#define MM 1600
#define KK 64
#define EPSF 1e-12f

typedef __attribute__((ext_vector_type(4))) float f32x4;
typedef __attribute__((ext_vector_type(8))) short bf16x8;

__device__ inline unsigned short f2bf(float f) {
    unsigned int u = __float_as_uint(f);
    unsigned int r = u + 0x7fffu + ((u >> 16) & 1u);   // RNE
    return (unsigned short)(r >> 16);
}

// ---------------------------------------------------------------------------
// w -> bf16
// ---------------------------------------------------------------------------
__global__ __launch_bounds__(256) void wconv_kernel(
    const float* __restrict__ w, unsigned short* __restrict__ wb)
{
    const int i = (blockIdx.x * 256 + threadIdx.x) * 8;
    float4 a = *(const float4*)(w + i);
    float4 b = *(const float4*)(w + i + 4);
    ushort4 u0, u1;
    u0.x = f2bf(a.x); u0.y = f2bf(a.y); u0.z = f2bf(a.z); u0.w = f2bf(a.w);
    u1.x = f2bf(b.x); u1.y = f2bf(b.y); u1.z = f2bf(b.z); u1.w = f2bf(b.w);
    *(ushort4*)(wb + i) = u0;
    *(ushort4*)(wb + i + 4) = u1;
}

// ---------------------------------------------------------------------------
// fused1 (R4-proven): per (n, 64-m tile): x scalar-coalesced from global,
// cvt->bf16 B-frag in-reg, MFMA logits, sumsq->rnorm via shfl, softmax over K,
// ap = a*rnorm bf16 [k][m], asum partials. grid (25, 64), block 256.
// ---------------------------------------------------------------------------
__global__ __launch_bounds__(256) void fused1_kernel(
    const float* __restrict__ x, const unsigned short* __restrict__ wb,
    const float* __restrict__ bias,
    unsigned short* __restrict__ ap, float* __restrict__ asum_part)
{
    __shared__ float als[64][68];   // a (unscaled), [k][m]
    __shared__ float rn_s[64];

    const int t  = threadIdx.x;
    const int n  = blockIdx.y;
    const int mt = blockIdx.x;
    const int m0 = mt * 64;
    const int wv   = t >> 6;
    const int lane = t & 63;
    const int g    = lane >> 4;   // 0..3
    const int lr   = lane & 15;
    const int m_lane = m0 + wv * 16 + lr;

    f32x4 acc[4];
    #pragma unroll
    for (int kt = 0; kt < 4; ++kt) acc[kt] = (f32x4){0.f, 0.f, 0.f, 0.f};

    float ss = 0.f;
    const float* xcol = x + (size_t)n * CC * MM + m_lane;
    const unsigned short* wrow = wb + g * 8;

    #pragma unroll 2
    for (int cs = 0; cs < 16; ++cs) {
        const int cbase = cs * 32 + g * 8;
        float xv[8];
        #pragma unroll
        for (int j = 0; j < 8; ++j) xv[j] = xcol[(size_t)(cbase + j) * MM];
        bf16x8 bfrag;
        #pragma unroll
        for (int j = 0; j < 8; ++j) {
            ss += xv[j] * xv[j];
            bfrag[j] = (short)f2bf(xv[j]);
        }
        #pragma unroll
        for (int kt = 0; kt < 4; ++kt) {
            bf16x8 afrag = *(const bf16x8*)(wrow + (kt * 16 + lr) * CC + cs * 32);
            acc[kt] = __builtin_amdgcn_mfma_f32_16x16x32_bf16(afrag, bfrag, acc[kt], 0, 0, 0);
        }
    }

    ss += __shfl_xor(ss, 16);
    ss += __shfl_xor(ss, 32);
    const float rnm = 1.0f / fmaxf(sqrtf(ss), EPSF);
    if (g == 0) rn_s[wv * 16 + lr] = rnm;

    float l[16];
    #pragma unroll
    for (int kt = 0; kt < 4; ++kt) {
        float4 bb = *(const float4*)(bias + kt * 16 + g * 4);
        l[kt * 4 + 0] = acc[kt][0] * rnm + bb.x;
        l[kt * 4 + 1] = acc[kt][1] * rnm + bb.y;
        l[kt * 4 + 2] = acc[kt][2] * rnm + bb.z;
        l[kt * 4 + 3] = acc[kt][3] * rnm + bb.w;
    }
    float mx = l[0];
    #pragma unroll
    for (int i = 1; i < 16; ++i) mx = fmaxf(mx, l[i]);
    mx = fmaxf(mx, __shfl_xor(mx, 16));
    mx = fmaxf(mx, __shfl_xor(mx, 32));
    float s = 0.f;
    #pragma unroll
    for (int i = 0; i < 16; ++i) { l[i] = __expf(l[i] - mx); s += l[i]; }
    s += __shfl_xor(s, 16);
    s += __shfl_xor(s, 32);
    const float inv = 1.0f / s;
    #pragma unroll
    for (int kt = 0; kt < 4; ++kt)
        #pragma unroll
        for (int r = 0; r < 4; ++r)
            als[kt * 16 + g * 4 + r][wv * 16 + lr] = l[kt * 4 + r] * inv;
    __syncthreads();

    {
        const int k = t >> 2, q = t & 3;
        float spart = 0.f;
        unsigned short ub[16];
        #pragma unroll
        for (int i = 0; i < 16; ++i) {
            float a = als[k][q * 16 + i];
            spart += a;
            ub[i] = f2bf(a * rn_s[q * 16 + i]);
        }
        unsigned short* dst = ap + ((size_t)(n * KK + k)) * MM + m0 + q * 16;
        *(uint4*)dst = *(uint4*)&ub[0];
        *(uint4*)(dst + 8) = *(uint4*)&ub[8];
        spart += __shfl_xor(spart, 1);
        spart += __shfl_xor(spart, 2);
        if (q == 0) asum_part[((size_t)(n * 25 + mt)) * 64 + k] = spart;
    }
}

// ---------------------------------------------------------------------------
// aggm (R4 access pattern + m-split x2): D[k64][c16/wave] = sum_m a'[k][m] *
// bf16(x[c][m]); x read f32 strided from global (L3-hot), a' via LDS.
// grid (8 ct, 2 mh, 64 n), block 256 -> 1024 blocks. Partial agg stores.
// ---------------------------------------------------------------------------
__global__ __launch_bounds__(256) void aggm_kernel(
    const float* __restrict__ x, const unsigned short* __restrict__ ap,
    float* __restrict__ aggp)
{
    __shared__ __attribute__((aligned(16))) unsigned short als2[64][72];
    const int t    = threadIdx.x;
    const int ct   = blockIdx.x;
    const int mh   = blockIdx.y;
    const int n    = blockIdx.z;
    const int wv   = t >> 6;
    const int lane = t & 63;
    const int g    = lane >> 4;
    const int lr   = lane & 15;
    const int c_w  = ct * 64 + wv * 16;

    f32x4 acc[4];
    #pragma unroll
    for (int kt = 0; kt < 4; ++kt) acc[kt] = (f32x4){0.f, 0.f, 0.f, 0.f};

    const int ks = t >> 2, qs = t & 3;   // staging coords
    const float* xrow = x + ((size_t)(n * CC + c_w + lr)) * MM;

    const int mc_beg = mh ? 832 : 0;     // 13 tiles | 12 tiles
    const int mc_end = mh ? MM : 832;

    for (int mc = mc_beg; mc < mc_end; mc += 64) {
        __syncthreads();
        {
            const unsigned short* src = ap + ((size_t)(n * KK + ks)) * MM + mc + qs * 16;
            uint4 w0 = *(const uint4*)src;
            uint4 w1 = *(const uint4*)(src + 8);
            *(uint4*)&als2[ks][qs * 16] = w0;
            *(uint4*)&als2[ks][qs * 16 + 8] = w1;
        }
        __syncthreads();
        #pragma unroll
        for (int msi = 0; msi < 2; ++msi) {
            const int ms = msi * 32;
            float4 v0 = *(const float4*)(xrow + mc + ms + g * 8);
            float4 v1 = *(const float4*)(xrow + mc + ms + g * 8 + 4);
            bf16x8 bf;
            bf[0] = (short)f2bf(v0.x); bf[1] = (short)f2bf(v0.y);
            bf[2] = (short)f2bf(v0.z); bf[3] = (short)f2bf(v0.w);
            bf[4] = (short)f2bf(v1.x); bf[5] = (short)f2bf(v1.y);
            bf[6] = (short)f2bf(v1.z); bf[7] = (short)f2bf(v1.w);
            #pragma unroll
            for (int kt = 0; kt < 4; ++kt) {
                bf16x8 af = *(const bf16x8*)&als2[kt * 16 + lr][ms + g * 8];
                acc[kt] = __builtin_amdgcn_mfma_f32_16x16x32_bf16(af, bf, acc[kt], 0, 0, 0);
            }
        }
    }
    #pragma unroll
    for (int kt = 0; kt < 4; ++kt)
        #pragma unroll
        for (int r = 0; r < 4; ++r) {
            const int k = kt * 16 + g * 4 + r;
            aggp[((size_t)((mh * NN + n) * KK + k)) * CC + c_w + lr] = acc[kt][r];
        }
}

// ---------------------------------------------------------------------------
// vlad = (agg0+agg1) - asum*cent, intra-normalize over C, apply global scale
// 0.125 (each intra-normalized block has unit norm -> global norm = sqrt(64);
// deviation from the reference's numeric global norm is ~1e-7 relative).
// ---------------------------------------------------------------------------
__global__ __launch_bounds__(256) void vlad_kernel(
    const float* __restrict__ aggp, const float* __restrict__ asum_part,
    const float* __restrict__ cent, float* __restrict__ out)
{
    __shared__ float wsum[4];
    __shared__ float sinv;
    const int nk = blockIdx.x;          // n*64 + k
    const int n = nk >> 6, k = nk & 63;
    const int t = threadIdx.x;
    const int u = t & 63;
    const size_t half = (size_t)NN * KK * CC;

    // reduce asum over 25 m-tile partials (each wave redundantly)
    float pa = (u < 25) ? asum_part[((size_t)(n * 25 + u)) * 64 + k] : 0.f;
    #pragma unroll
    for (int o = 32; o > 0; o >>= 1) pa += __shfl_xor(pa, o);
    const float s = pa;

    float2 a0 = *(const float2*)(aggp + (size_t)nk * CC + 2 * t);
    float2 a1 = *(const float2*)(aggp + half + (size_t)nk * CC + 2 * t);
    float2 cv = *(const float2*)(cent + (size_t)k * CC + 2 * t);
    float v0 = (a0.x + a1.x) - s * cv.x;
    float v1 = (a0.y + a1.y) - s * cv.y;
    float ss = v0 * v0 + v1 * v1;
    #pragma unroll
    for (int o = 32; o > 0; o >>= 1) ss += __shfl_down(ss, o);
    int wid = t >> 6;
    if (u == 0) wsum[wid] = ss;
    __syncthreads();
    if (t == 0) {
        float tot = wsum[0] + wsum[1] + wsum[2] + wsum[3];
        sinv = 1.0f / fmaxf(sqrtf(tot), EPSF);
    }
    __syncthreads();
    const float sc = sinv * 0.125f;
    float2 o2; o2.x = v0 * sc; o2.y = v1 * sc;
    *(float2*)(out + (size_t)nk * CC + 2 * t) = o2;
}

extern "C" void kernel_launch(void* const* d_in, const int* in_sizes, int n_in,
                              void* d_out, int out_size, void* d_ws, size_t ws_size,
                              hipStream_t stream)
{
    const float* x    = (const float*)d_in[0];
    const float* w    = (const float*)d_in[1];
    const float* bias = (const float*)d_in[2];
    const float* cent = (const float*)d_in[3];
    float* out = (float*)d_out;

    char* ws = (char*)d_ws;
    size_t off = 0;
    unsigned short* ap  = (unsigned short*)(ws + off); off += (size_t)NN * KK * MM * 2;
    unsigned short* wb  = (unsigned short*)(ws + off); off += (size_t)KK * CC * 2;
    float* aggp      = (float*)(ws + off); off += (size_t)2 * NN * KK * CC * 4;
    float* asum_part = (float*)(ws + off); off += (size_t)NN * 25 * KK * 4;

    wconv_kernel <<<16, 256, 0, stream>>>(w, wb);
    fused1_kernel<<<dim3(25, 64), 256, 0, stream>>>(x, wb, bias, ap, asum_part);
    aggm_kernel  <<<dim3(8, 2, 64), 256, 0, stream>>>(x, ap, aggp);
    vlad_kernel  <<<NN * KK, 256, 0, stream>>>(aggp, asum_part, cent, out);
}